// Round 1
// baseline (768.612 us; speedup 1.0000x reference)
//
#include <hip/hip_runtime.h>
#include <stdint.h>

#define NTOK 49
#define DIM 256
#define NH 8
#define HD 32
#define NWIN 4096

typedef short bf16x8 __attribute__((ext_vector_type(8)));
typedef float f32x4 __attribute__((ext_vector_type(4)));

__device__ __forceinline__ unsigned short f2bf(float f) {
    union { float f; unsigned int u; } v; v.f = f;
    unsigned int r = v.u + 0x7FFFu + ((v.u >> 16) & 1u);
    return (unsigned short)(r >> 16);
}

__device__ __forceinline__ f32x4 mfma16(bf16x8 a, bf16x8 b, f32x4 c) {
    return __builtin_amdgcn_mfma_f32_16x16x32_bf16(a, b, c, 0, 0, 0);
}

__device__ __forceinline__ bf16x8 ld8s(const unsigned short* p) {
    return *(const bf16x8*)p;
}

// ---------------------------------------------------------------------------
// K0: convert weights to bf16, expand relative-position bias to [8][64][64]
// with the key-padding mask (-1e30 for key col >= 49) baked in.
// ---------------------------------------------------------------------------
__global__ void prep_kernel(const float* __restrict__ qkv_w,
                            const float* __restrict__ proj_w,
                            const float* __restrict__ bias_table,
                            const int* __restrict__ rel_idx,
                            unsigned short* __restrict__ wqkv,
                            unsigned short* __restrict__ wproj,
                            float* __restrict__ biasx)
{
    int i0 = blockIdx.x * blockDim.x + threadIdx.x;
    int stride = gridDim.x * blockDim.x;
    for (int t = i0; t < 768 * 256; t += stride) wqkv[t] = f2bf(qkv_w[t]);
    for (int t = i0; t < 256 * 256; t += stride) wproj[t] = f2bf(proj_w[t]);
    for (int t = i0; t < NH * 64 * 64; t += stride) {
        int h = t >> 12;
        int m = (t >> 6) & 63;
        int n = t & 63;
        float v;
        if (n >= NTOK)      v = -1e30f;   // masked key column (exp -> 0)
        else if (m >= NTOK) v = 0.0f;     // pad query row, never emitted
        else                v = bias_table[rel_idx[m * NTOK + n] * NH + h];
        biasx[t] = v;
    }
}

// ---------------------------------------------------------------------------
// K1: per-window fused QKV GEMM + attention. 256 threads = 4 waves.
// 4 passes x 2 heads. A-fragments of x held in 128 VGPRs for the whole
// kernel; the x LDS region is recycled as the P (softmax probs) buffer.
// ---------------------------------------------------------------------------
__global__ __launch_bounds__(256, 2) void attn_kernel(
    const float* __restrict__ x,
    const float* __restrict__ qkv_b,
    const unsigned short* __restrict__ wqkv,
    const float* __restrict__ biasx,
    unsigned short* __restrict__ aout)
{
    // LDS: strides padded so every ds_read_b128 is 16B-aligned and <=2-way
    // bank aliasing (free on CDNA4).
    __shared__ unsigned short xs[64 * 264];      // x bf16 [64][264]; later P[2][64][72]
    __shared__ unsigned short qs[2 * 64 * 40];   // q*scale bf16 [head][tok][40]
    __shared__ unsigned short ks[2 * 64 * 40];   // k bf16 [head][tok][40]
    __shared__ unsigned short vt[2 * 32 * 72];   // v^T bf16 [head][d][72]

    const int tid  = threadIdx.x;
    const int wave = tid >> 6;
    const int lane = tid & 63;
    const int l16  = lane & 15;
    const int lq   = lane >> 4;
    const int w    = blockIdx.x;
    const float scale = 0.17677669529663687f;   // 32^-0.5

    // ---- stage x (fp32 -> bf16) into LDS, zero pad rows 49..63 ----
    const float* xw = x + (size_t)w * (NTOK * DIM);
    for (int idx = tid * 4; idx < NTOK * DIM; idx += 256 * 4) {
        float4 f = *(const float4*)(xw + idx);
        int r = idx >> 8, c = idx & 255;
        unsigned short* d = &xs[r * 264 + c];
        d[0] = f2bf(f.x); d[1] = f2bf(f.y); d[2] = f2bf(f.z); d[3] = f2bf(f.w);
    }
    for (int idx = tid; idx < 15 * 264; idx += 256)
        xs[49 * 264 + idx] = 0;
    __syncthreads();

    // ---- hoist all x A-fragments into registers (4 m-tiles x 8 k-chunks) ----
    bf16x8 afrag[4][8];
#pragma unroll
    for (int mt = 0; mt < 4; ++mt)
#pragma unroll
        for (int c = 0; c < 8; ++c)
            afrag[mt][c] = ld8s(&xs[(mt * 16 + l16) * 264 + c * 32 + lq * 8]);

    unsigned short* Pbuf = xs;   // P[head_local][64][72], 18432 B, fits in xs

    for (int p = 0; p < 4; ++p) {
        // ---- partial QKV GEMM: 12 n-tiles (q/k/v for heads 2p, 2p+1) ----
#pragma unroll
        for (int ti = 0; ti < 3; ++ti) {
            int tl   = wave * 3 + ti;          // 0..11
            int grp  = tl >> 2;                // 0=q 1=k 2=v
            int sub  = tl & 3;
            int tile = grp * 16 + p * 4 + sub; // global n-tile (of 48)
            int ch   = tile * 16 + l16;        // output channel 0..767

            const unsigned short* bptr = wqkv + (size_t)ch * 256 + lq * 8;
            bf16x8 bfr[8];
#pragma unroll
            for (int c = 0; c < 8; ++c)
                bfr[c] = ld8s(bptr + c * 32);

            f32x4 acc[4];
#pragma unroll
            for (int mt = 0; mt < 4; ++mt) {
                f32x4 z = {0.f, 0.f, 0.f, 0.f};
                acc[mt] = z;
            }
#pragma unroll
            for (int c = 0; c < 8; ++c)
#pragma unroll
                for (int mt = 0; mt < 4; ++mt)
                    acc[mt] = mfma16(afrag[mt][c], bfr[c], acc[mt]);

            float bv  = qkv_b[ch];
            int   chm = ch & 255;
            int   hl  = (chm >> 5) & 1;
            int   d   = chm & 31;
#pragma unroll
            for (int mt = 0; mt < 4; ++mt)
#pragma unroll
                for (int r = 0; r < 4; ++r) {
                    int row = mt * 16 + lq * 4 + r;
                    float v = acc[mt][r] + bv;
                    if (grp == 0)      qs[(hl * 64 + row) * 40 + d] = f2bf(v * scale);
                    else if (grp == 1) ks[(hl * 64 + row) * 40 + d] = f2bf(v);
                    else               vt[(hl * 32 + d) * 72 + row] = f2bf(v);
                }
        }
        __syncthreads();

        // ---- attention: wave -> (head = 2p + wave>>1, m-half = wave&1) ----
        {
            int hl = wave >> 1;
            int h  = 2 * p + hl;
            int mh = wave & 1;

            // S = (q*scale) K^T  (K=32 -> one MFMA per 16x16 tile)
            bf16x8 qf[2];
#pragma unroll
            for (int i = 0; i < 2; ++i)
                qf[i] = ld8s(&qs[(hl * 64 + (2 * mh + i) * 16 + l16) * 40 + lq * 8]);

            f32x4 sacc[2][4];
#pragma unroll
            for (int i = 0; i < 2; ++i)
#pragma unroll
                for (int nt = 0; nt < 4; ++nt) {
                    f32x4 z = {0.f, 0.f, 0.f, 0.f};
                    sacc[i][nt] = z;
                }
#pragma unroll
            for (int nt = 0; nt < 4; ++nt) {
                bf16x8 kf = ld8s(&ks[(hl * 64 + nt * 16 + l16) * 40 + lq * 8]);
#pragma unroll
                for (int i = 0; i < 2; ++i)
                    sacc[i][nt] = mfma16(qf[i], kf, sacc[i][nt]);
            }

            // bias + fp32 softmax (rows live in 16-lane groups), write P bf16
            const float* bh = biasx + h * 4096;
            float pr[2][4];
#pragma unroll
            for (int i = 0; i < 2; ++i) {
                int mt = 2 * mh + i;
#pragma unroll
                for (int r = 0; r < 4; ++r) {
                    int row = mt * 16 + lq * 4 + r;
                    float s0 = sacc[i][0][r] + bh[row * 64 +  0 + l16];
                    float s1 = sacc[i][1][r] + bh[row * 64 + 16 + l16];
                    float s2 = sacc[i][2][r] + bh[row * 64 + 32 + l16];
                    float s3 = sacc[i][3][r] + bh[row * 64 + 48 + l16];
                    float mx = fmaxf(fmaxf(s0, s1), fmaxf(s2, s3));
#pragma unroll
                    for (int off = 1; off < 16; off <<= 1)
                        mx = fmaxf(mx, __shfl_xor(mx, off));
                    float e0 = __expf(s0 - mx);
                    float e1 = __expf(s1 - mx);
                    float e2 = __expf(s2 - mx);
                    float e3 = __expf(s3 - mx);
                    float sum = e0 + e1 + e2 + e3;
#pragma unroll
                    for (int off = 1; off < 16; off <<= 1)
                        sum += __shfl_xor(sum, off);
                    pr[i][r] = 1.0f / sum;
                    unsigned short* Pr = Pbuf + (hl * 64 + row) * 72;
                    Pr[ 0 + l16] = f2bf(e0);
                    Pr[16 + l16] = f2bf(e1);
                    Pr[32 + l16] = f2bf(e2);
                    Pr[48 + l16] = f2bf(e3);
                }
            }

            // O = P V   (each wave reads only the P rows it wrote)
            f32x4 oacc[2][2];
#pragma unroll
            for (int i = 0; i < 2; ++i)
#pragma unroll
                for (int nt = 0; nt < 2; ++nt) {
                    f32x4 z = {0.f, 0.f, 0.f, 0.f};
                    oacc[i][nt] = z;
                }
#pragma unroll
            for (int kc = 0; kc < 2; ++kc) {
                bf16x8 pf[2];
#pragma unroll
                for (int i = 0; i < 2; ++i)
                    pf[i] = ld8s(&Pbuf[(hl * 64 + (2 * mh + i) * 16 + l16) * 72 + kc * 32 + lq * 8]);
#pragma unroll
                for (int nt = 0; nt < 2; ++nt) {
                    bf16x8 vf = ld8s(&vt[(hl * 32 + nt * 16 + l16) * 72 + kc * 32 + lq * 8]);
#pragma unroll
                    for (int i = 0; i < 2; ++i)
                        oacc[i][nt] = mfma16(pf[i], vf, oacc[i][nt]);
                }
            }

            // normalize + store attnout bf16 [win*49+row][h*32+d]
#pragma unroll
            for (int i = 0; i < 2; ++i)
#pragma unroll
                for (int r = 0; r < 4; ++r) {
                    int row = (2 * mh + i) * 16 + lq * 4 + r;
                    if (row < NTOK) {
                        size_t base = ((size_t)w * NTOK + row) * 256 + h * 32;
                        float rs = pr[i][r];
                        aout[base +      l16] = f2bf(oacc[i][0][r] * rs);
                        aout[base + 16 + l16] = f2bf(oacc[i][1][r] * rs);
                    }
                }
        }
        __syncthreads();   // before next pass overwrites qs/ks/vt/P
    }
}

// ---------------------------------------------------------------------------
// K2: output projection. M = 4096*49 = 200704 = 64*3136 (dense, no padding),
// N = K = 256. One block = 64 rows, 4 waves x 4 n-tiles.
// ---------------------------------------------------------------------------
__global__ __launch_bounds__(256, 2) void proj_kernel(
    const unsigned short* __restrict__ aout,
    const unsigned short* __restrict__ wproj,
    const float* __restrict__ proj_b,
    float* __restrict__ out)
{
    __shared__ unsigned short as_[64 * 264];

    const int tid  = threadIdx.x;
    const int wave = tid >> 6;
    const int lane = tid & 63;
    const int l16  = lane & 15;
    const int lq   = lane >> 4;
    const size_t mb = blockIdx.x;

    const unsigned short* arow = aout + mb * (64 * 256);
    for (int idx = tid * 8; idx < 64 * 256; idx += 256 * 8) {
        uint4 v = *(const uint4*)(arow + idx);
        int r = idx >> 8, c = idx & 255;
        *(uint4*)&as_[r * 264 + c] = v;
    }
    __syncthreads();

    bf16x8 af[4][8];
#pragma unroll
    for (int mt = 0; mt < 4; ++mt)
#pragma unroll
        for (int c = 0; c < 8; ++c)
            af[mt][c] = ld8s(&as_[(mt * 16 + l16) * 264 + c * 32 + lq * 8]);

#pragma unroll
    for (int nt4 = 0; nt4 < 4; ++nt4) {
        int nt = wave * 4 + nt4;
        int ch = nt * 16 + l16;
        const unsigned short* bptr = wproj + (size_t)ch * 256 + lq * 8;
        bf16x8 bfr[8];
#pragma unroll
        for (int c = 0; c < 8; ++c)
            bfr[c] = ld8s(bptr + c * 32);

        f32x4 acc[4];
#pragma unroll
        for (int mt = 0; mt < 4; ++mt) {
            f32x4 z = {0.f, 0.f, 0.f, 0.f};
            acc[mt] = z;
        }
#pragma unroll
        for (int c = 0; c < 8; ++c)
#pragma unroll
            for (int mt = 0; mt < 4; ++mt)
                acc[mt] = mfma16(af[mt][c], bfr[c], acc[mt]);

        float pb = proj_b[ch];
#pragma unroll
        for (int mt = 0; mt < 4; ++mt)
#pragma unroll
            for (int r = 0; r < 4; ++r) {
                size_t row = mb * 64 + mt * 16 + lq * 4 + r;
                out[row * 256 + ch] = acc[mt][r] + pb;
            }
    }
}

// ---------------------------------------------------------------------------
extern "C" void kernel_launch(void* const* d_in, const int* in_sizes, int n_in,
                              void* d_out, int out_size, void* d_ws, size_t ws_size,
                              hipStream_t stream) {
    const float* x          = (const float*)d_in[0];
    const float* qkv_w      = (const float*)d_in[1];
    const float* qkv_b      = (const float*)d_in[2];
    const float* proj_w     = (const float*)d_in[3];
    const float* proj_b     = (const float*)d_in[4];
    const float* bias_table = (const float*)d_in[5];
    const int*   rel_idx    = (const int*)d_in[6];
    float* out = (float*)d_out;

    char* ws = (char*)d_ws;
    unsigned short* wqkv  = (unsigned short*)ws;                 // 393216 B
    unsigned short* wproj = (unsigned short*)(ws + 393216);      // 131072 B
    float*          biasx = (float*)(ws + 524288);               // 131072 B
    unsigned short* aout  = (unsigned short*)(ws + 655360);      // 102760448 B

    prep_kernel<<<256, 256, 0, stream>>>(qkv_w, proj_w, bias_table, rel_idx,
                                         wqkv, wproj, biasx);
    attn_kernel<<<NWIN, 256, 0, stream>>>(x, qkv_b, wqkv, biasx, aout);
    proj_kernel<<<3136, 256, 0, stream>>>(aout, wproj, proj_b, out);
}

// Round 2
// 695.142 us; speedup vs baseline: 1.1057x; 1.1057x over previous
//
#include <hip/hip_runtime.h>
#include <hip/hip_bf16.h>
#include <stdint.h>

#define NTOK 49
#define NH 8
#define NWIN 4096

typedef short bf16x8 __attribute__((ext_vector_type(8)));
typedef float f32x4 __attribute__((ext_vector_type(4)));

__device__ __forceinline__ f32x4 mfma16(bf16x8 a, bf16x8 b, f32x4 c) {
    return __builtin_amdgcn_mfma_f32_16x16x32_bf16(a, b, c, 0, 0, 0);
}
__device__ __forceinline__ bf16x8 ld8s(const unsigned short* p) {
    return *(const bf16x8*)p;
}
// packed fp32x2 -> bf16x2 (v_cvt_pk_bf16_f32 on gfx950)
__device__ __forceinline__ unsigned int pk2bf(float a, float b) {
    __hip_bfloat162 h = __float22bfloat162_rn(float2{a, b});
    return *reinterpret_cast<unsigned int*>(&h);
}
// store 4 floats as 4 consecutive bf16 (8B-aligned ds_write_b64)
__device__ __forceinline__ void st4bf(unsigned short* p, float a, float b, float c, float d) {
    uint2 u;
    u.x = pk2bf(a, b);
    u.y = pk2bf(c, d);
    *reinterpret_cast<uint2*>(p) = u;
}
__device__ __forceinline__ bf16x8 pk8(float4 f0, float4 f1) {
    union { bf16x8 v; unsigned int u[4]; } t;
    t.u[0] = pk2bf(f0.x, f0.y);
    t.u[1] = pk2bf(f0.z, f0.w);
    t.u[2] = pk2bf(f1.x, f1.y);
    t.u[3] = pk2bf(f1.z, f1.w);
    return t.v;
}
__device__ __forceinline__ unsigned short f2bf(float f) {
    union { float f; unsigned int u; } v; v.f = f;
    unsigned int r = v.u + 0x7FFFu + ((v.u >> 16) & 1u);
    return (unsigned short)(r >> 16);
}

// ---------------------------------------------------------------------------
// K0: weights -> bf16; expand rel-pos bias to [8][64][64] fp32 with key
// padding mask baked in (-1e30 on key cols >= 49 -> exp() == 0).
// ---------------------------------------------------------------------------
__global__ void prep_kernel(const float* __restrict__ qkv_w,
                            const float* __restrict__ proj_w,
                            const float* __restrict__ bias_table,
                            const int* __restrict__ rel_idx,
                            unsigned short* __restrict__ wqkv,
                            unsigned short* __restrict__ wproj,
                            float* __restrict__ biasx)
{
    int i0 = blockIdx.x * blockDim.x + threadIdx.x;
    int stride = gridDim.x * blockDim.x;
    for (int t = i0; t < 768 * 256; t += stride) wqkv[t] = f2bf(qkv_w[t]);
    for (int t = i0; t < 256 * 256; t += stride) wproj[t] = f2bf(proj_w[t]);
    for (int t = i0; t < NH * 64 * 64; t += stride) {
        int h = t >> 12;
        int m = (t >> 6) & 63;   // query row
        int n = t & 63;          // key col
        float v;
        if (n >= NTOK)      v = -1e30f;
        else if (m >= NTOK) v = 0.0f;
        else                v = bias_table[rel_idx[m * NTOK + n] * NH + h];
        biasx[t] = v;
    }
}

// ---------------------------------------------------------------------------
// K1: fully fused per-window QKV + attention + proj. 256 thr = 4 waves.
// 4 passes x 2 heads, then in-block projection from the LDS attnout tile.
//
// Layout conventions (mfma_f32_16x16x32_bf16):
//   A-frag: a[m = lane&15][k = (lane>>4)*8 + j]
//   B-frag: b[n = lane&15][k = (lane>>4)*8 + j]
//   C/D   : col(n) = lane&15, row(m) = (lane>>4)*4 + reg
// "Swapped" GEMMs (W as A, x as B) put channels in regs -> packed b64 LDS
// writes; Sᵀ (K as A, Q as B) puts keys in regs -> in-lane softmax.
// ---------------------------------------------------------------------------
__global__ __launch_bounds__(256, 2) void fused_kernel(
    const float* __restrict__ x,
    const float* __restrict__ qkv_b,
    const unsigned short* __restrict__ wqkv,
    const float* __restrict__ biasx,
    const unsigned short* __restrict__ wproj,
    const float* __restrict__ proj_b,
    float* __restrict__ out)
{
    // 63488 B total -> 2 blocks/CU
    __shared__ unsigned short smem[31744];
    unsigned short* ao = smem;           // [64][264] attnout bf16
    unsigned short* qs = smem + 16896;   // [2][64][40] q*scale
    unsigned short* ks = qs + 5120;      // [2][64][40] k
    unsigned short* vt = qs + 10240;     // [2][32][72] v^T
    unsigned short* Pb = qs;             // [2][64][72] probs, aliases qs+ks

    const int tid  = threadIdx.x;
    const int wave = tid >> 6;
    const int lane = tid & 63;
    const int l16  = lane & 15;
    const int lq   = lane >> 4;
    const int w    = blockIdx.x;
    const float scale = 0.17677669529663687f;   // 32^-0.5

    // ---- x A-fragments straight from global (fp32 -> bf16), pad rows = 0 ----
    const float* xw = x + (size_t)w * (NTOK * 256);
    bf16x8 afrag[4][8];
#pragma unroll
    for (int mt = 0; mt < 4; ++mt) {
        int tok = mt * 16 + l16;
#pragma unroll
        for (int c = 0; c < 8; ++c) {
            if (tok < NTOK) {
                const float* p = xw + tok * 256 + c * 32 + lq * 8;
                float4 f0 = *(const float4*)p;
                float4 f1 = *(const float4*)(p + 4);
                afrag[mt][c] = pk8(f0, f1);
            } else {
                union { bf16x8 v; unsigned int u[4]; } z;
                z.u[0] = z.u[1] = z.u[2] = z.u[3] = 0;
                afrag[mt][c] = z.v;
            }
        }
    }

    const int hl = wave >> 1;   // head-local within pass
    const int mh = wave & 1;    // query half

#pragma unroll 1
    for (int p = 0; p < 4; ++p) {
        // ================= QKV partial GEMM (2 heads) =================
#pragma unroll
        for (int ti = 0; ti < 3; ++ti) {
            int tl   = wave * 3 + ti;          // 0..11
            int grp  = tl >> 2;                // 0=q 1=k 2=v
            int sub  = tl & 3;
            int tile = grp * 16 + p * 4 + sub; // of 48
            const unsigned short* bptr = wqkv + (size_t)(tile * 16 + l16) * 256 + lq * 8;
            bf16x8 bfr[8];
#pragma unroll
            for (int c = 0; c < 8; ++c) bfr[c] = ld8s(bptr + c * 32);

            f32x4 acc[4];
#pragma unroll
            for (int i = 0; i < 4; ++i) { f32x4 z = {0.f,0.f,0.f,0.f}; acc[i] = z; }

            if (grp < 2) {
                // swapped: D[ch][tok] -> packed writes along d
#pragma unroll
                for (int c = 0; c < 8; ++c)
#pragma unroll
                    for (int nt = 0; nt < 4; ++nt)
                        acc[nt] = mfma16(bfr[c], afrag[nt][c], acc[nt]);
                int chb = tile * 16 + lq * 4;          // global channel base
                float4 bv = *(const float4*)(qkv_b + chb);
                int c0 = chb & 255;
                int hh = (c0 >> 5) & 1, d0 = c0 & 31;
                unsigned short* dst = (grp == 0 ? qs : ks) + (hh * 64) * 40 + d0;
                float sc = (grp == 0) ? scale : 1.0f;
#pragma unroll
                for (int nt = 0; nt < 4; ++nt) {
                    int tok = nt * 16 + l16;
                    st4bf(dst + tok * 40,
                          (acc[nt][0] + bv.x) * sc, (acc[nt][1] + bv.y) * sc,
                          (acc[nt][2] + bv.z) * sc, (acc[nt][3] + bv.w) * sc);
                }
            } else {
                // original: D[tok][ch] -> packed writes along tok into v^T
#pragma unroll
                for (int c = 0; c < 8; ++c)
#pragma unroll
                    for (int mt = 0; mt < 4; ++mt)
                        acc[mt] = mfma16(afrag[mt][c], bfr[c], acc[mt]);
                int ch = tile * 16 + l16;
                float bv = qkv_b[ch];
                int c0 = ch & 255;
                int hh = (c0 >> 5) & 1, d = c0 & 31;
                unsigned short* dst = vt + (hh * 32 + d) * 72;
#pragma unroll
                for (int mt = 0; mt < 4; ++mt) {
                    int tok0 = mt * 16 + lq * 4;
                    st4bf(dst + tok0, acc[mt][0] + bv, acc[mt][1] + bv,
                                      acc[mt][2] + bv, acc[mt][3] + bv);
                }
            }
        }
        __syncthreads();   // (B) q/k/v visible

        // ================= attention: Sᵀ = K·Qᵀ =================
        const int h = 2 * p + hl;
        bf16x8 kf[4], qf[2];
#pragma unroll
        for (int mt = 0; mt < 4; ++mt)
            kf[mt] = ld8s(&ks[(hl * 64 + mt * 16 + l16) * 40 + lq * 8]);
#pragma unroll
        for (int ni = 0; ni < 2; ++ni)
            qf[ni] = ld8s(&qs[(hl * 64 + mh * 32 + ni * 16 + l16) * 40 + lq * 8]);

        f32x4 se[4][2];
#pragma unroll
        for (int mt = 0; mt < 4; ++mt)
#pragma unroll
            for (int ni = 0; ni < 2; ++ni) { f32x4 z = {0.f,0.f,0.f,0.f}; se[mt][ni] = z; }
#pragma unroll
        for (int mt = 0; mt < 4; ++mt)
#pragma unroll
            for (int ni = 0; ni < 2; ++ni)
                se[mt][ni] = mfma16(kf[mt], qf[ni], se[mt][ni]);
        // lane holds: query = mh*32 + ni*16 + l16, key = mt*16 + lq*4 + r

        // bias + exp + in-lane sum (no max-subtract: |s| bounded ~15)
        const float* bh = biasx + (h << 12);
        float rinv[2];
#pragma unroll
        for (int ni = 0; ni < 2; ++ni) {
            int q = mh * 32 + ni * 16 + l16;
            float lsum = 0.0f;
#pragma unroll
            for (int mt = 0; mt < 4; ++mt) {
                float4 bb = *(const float4*)(bh + q * 64 + mt * 16 + lq * 4);
                float e0 = __expf(se[mt][ni][0] + bb.x);
                float e1 = __expf(se[mt][ni][1] + bb.y);
                float e2 = __expf(se[mt][ni][2] + bb.z);
                float e3 = __expf(se[mt][ni][3] + bb.w);
                se[mt][ni][0] = e0; se[mt][ni][1] = e1;
                se[mt][ni][2] = e2; se[mt][ni][3] = e3;
                lsum += (e0 + e1) + (e2 + e3);
            }
            lsum += __shfl_xor(lsum, 16);
            lsum += __shfl_xor(lsum, 32);
            rinv[ni] = 1.0f / lsum;
        }
        __syncthreads();   // (C) all q/k frag reads done before P overwrites

        // normalized P, row-major [query][key], packed b64 writes
#pragma unroll
        for (int ni = 0; ni < 2; ++ni) {
            int q = mh * 32 + ni * 16 + l16;
            float rv = rinv[ni];
#pragma unroll
            for (int mt = 0; mt < 4; ++mt)
                st4bf(&Pb[(hl * 64 + q) * 72 + mt * 16 + lq * 4],
                      se[mt][ni][0] * rv, se[mt][ni][1] * rv,
                      se[mt][ni][2] * rv, se[mt][ni][3] * rv);
        }
        __threadfence_block();  // same-wave LDS RAW (only this wave reads its P rows)

        // ================= Oᵀ = Vᵀ·P =================
        bf16x8 vf[2][2], pf[2][2];
#pragma unroll
        for (int kc = 0; kc < 2; ++kc) {
#pragma unroll
            for (int mt = 0; mt < 2; ++mt)
                vf[mt][kc] = ld8s(&vt[(hl * 32 + mt * 16 + l16) * 72 + kc * 32 + lq * 8]);
#pragma unroll
            for (int ni = 0; ni < 2; ++ni)
                pf[ni][kc] = ld8s(&Pb[(hl * 64 + mh * 32 + ni * 16 + l16) * 72 + kc * 32 + lq * 8]);
        }
        f32x4 ot[2][2];
#pragma unroll
        for (int mt = 0; mt < 2; ++mt)
#pragma unroll
            for (int ni = 0; ni < 2; ++ni) { f32x4 z = {0.f,0.f,0.f,0.f}; ot[mt][ni] = z; }
#pragma unroll
        for (int kc = 0; kc < 2; ++kc)
#pragma unroll
            for (int mt = 0; mt < 2; ++mt)
#pragma unroll
                for (int ni = 0; ni < 2; ++ni)
                    ot[mt][ni] = mfma16(vf[mt][kc], pf[ni][kc], ot[mt][ni]);
        // lane holds: d = mt*16 + lq*4 + r, query = ni*16 + l16 (+mh*32)

#pragma unroll
        for (int mt = 0; mt < 2; ++mt)
#pragma unroll
            for (int ni = 0; ni < 2; ++ni) {
                int q = mh * 32 + ni * 16 + l16;
                st4bf(&ao[q * 264 + h * 32 + mt * 16 + lq * 4],
                      ot[mt][ni][0], ot[mt][ni][1], ot[mt][ni][2], ot[mt][ni][3]);
            }
        __syncthreads();   // (E) P/vt consumed before next pass's epilogue
    }

    // ================= projection from LDS attnout =================
    bf16x8 af2[4][8];
#pragma unroll
    for (int nt = 0; nt < 4; ++nt)
#pragma unroll
        for (int c = 0; c < 8; ++c)
            af2[nt][c] = ld8s(&ao[(nt * 16 + l16) * 264 + c * 32 + lq * 8]);

#pragma unroll
    for (int t4 = 0; t4 < 4; ++t4) {
        int tile = wave * 4 + t4;          // 16 channel-tiles
        const unsigned short* wp = wproj + (size_t)(tile * 16 + l16) * 256 + lq * 8;
        bf16x8 wfr[8];
#pragma unroll
        for (int c = 0; c < 8; ++c) wfr[c] = ld8s(wp + c * 32);

        f32x4 acc[4];
#pragma unroll
        for (int i = 0; i < 4; ++i) { f32x4 z = {0.f,0.f,0.f,0.f}; acc[i] = z; }
#pragma unroll
        for (int c = 0; c < 8; ++c)
#pragma unroll
            for (int nt = 0; nt < 4; ++nt)
                acc[nt] = mfma16(wfr[c], af2[nt][c], acc[nt]);

        int chb = tile * 16 + lq * 4;
        float4 pb = *(const float4*)(proj_b + chb);
#pragma unroll
        for (int nt = 0; nt < 4; ++nt) {
            int tok = nt * 16 + l16;
            if (tok < NTOK) {
                float4 o;
                o.x = acc[nt][0] + pb.x;
                o.y = acc[nt][1] + pb.y;
                o.z = acc[nt][2] + pb.z;
                o.w = acc[nt][3] + pb.w;
                *(float4*)(out + ((size_t)w * NTOK + tok) * 256 + chb) = o;
            }
        }
    }
}

// ---------------------------------------------------------------------------
extern "C" void kernel_launch(void* const* d_in, const int* in_sizes, int n_in,
                              void* d_out, int out_size, void* d_ws, size_t ws_size,
                              hipStream_t stream) {
    const float* x          = (const float*)d_in[0];
    const float* qkv_w      = (const float*)d_in[1];
    const float* qkv_b      = (const float*)d_in[2];
    const float* proj_w     = (const float*)d_in[3];
    const float* proj_b     = (const float*)d_in[4];
    const float* bias_table = (const float*)d_in[5];
    const int*   rel_idx    = (const int*)d_in[6];
    float* out = (float*)d_out;

    char* ws = (char*)d_ws;
    unsigned short* wqkv  = (unsigned short*)ws;                 // 393216 B
    unsigned short* wproj = (unsigned short*)(ws + 393216);      // 131072 B
    float*          biasx = (float*)(ws + 524288);               // 131072 B

    prep_kernel<<<256, 256, 0, stream>>>(qkv_w, proj_w, bias_table, rel_idx,
                                         wqkv, wproj, biasx);
    fused_kernel<<<NWIN, 256, 0, stream>>>(x, qkv_b, wqkv, biasx, wproj,
                                           proj_b, out);
}